// Round 4
// baseline (77.657 us; speedup 1.0000x reference)
//
#include <hip/hip_runtime.h>

// NodeConvolution: out[b,s,d] = x[b,2s,d]*w[0,d] + x[b,2s+1,d]*w[1,d]
// Shapes: x (32, 4096, 512) f32, w (2, 512) f32, out (32, 2048, 512) f32.
// Memory-bound: ~403 MB HBM traffic. R1: 79.2 us (5.09 TB/s).
// R3 (nontemporal + 2x unroll): 72.5 us (5.56 TB/s, 88% of copy ceiling).
// R4: 4x unroll, loads batched ahead of stores -> deeper vmcnt pipeline.

#define D4 128          // D/4 float4 per row
#define D4_SHIFT 7      // log2(D4)

typedef float f32x4 __attribute__((ext_vector_type(4)));

__global__ __launch_bounds__(256) void nodeconv_kernel(
    const f32x4* __restrict__ x,   // [B*N][D4]
    const f32x4* __restrict__ w,   // [2][D4]
    f32x4* __restrict__ out,       // [B*steps][D4]
    int n4)
{
    const int stride = gridDim.x * blockDim.x;   // multiple of D4 by construction
    const int tid = blockIdx.x * blockDim.x + threadIdx.x;

    // stride % D4 == 0 -> column index d is loop-invariant per thread
    const int d = tid & (D4 - 1);
    const f32x4 w0 = w[d];          // weights: tiny, cache-resident
    const f32x4 w1 = w[D4 + d];

    int i = tid;
    // main: 4 outputs per iteration; all 8 loads issued before any FMA/store
    for (; i + 3 * stride < n4; i += 4 * stride) {
        const int i0 = i;
        const int i1 = i + stride;
        const int i2 = i + 2 * stride;
        const int i3 = i + 3 * stride;
        const int r0 = i0 >> D4_SHIFT;
        const int r1 = i1 >> D4_SHIFT;
        const int r2 = i2 >> D4_SHIFT;
        const int r3 = i3 >> D4_SHIFT;
        const f32x4 a0 = __builtin_nontemporal_load(&x[((2 * r0)     << D4_SHIFT) + d]);
        const f32x4 a1 = __builtin_nontemporal_load(&x[((2 * r0 + 1) << D4_SHIFT) + d]);
        const f32x4 b0 = __builtin_nontemporal_load(&x[((2 * r1)     << D4_SHIFT) + d]);
        const f32x4 b1 = __builtin_nontemporal_load(&x[((2 * r1 + 1) << D4_SHIFT) + d]);
        const f32x4 c0 = __builtin_nontemporal_load(&x[((2 * r2)     << D4_SHIFT) + d]);
        const f32x4 c1 = __builtin_nontemporal_load(&x[((2 * r2 + 1) << D4_SHIFT) + d]);
        const f32x4 e0 = __builtin_nontemporal_load(&x[((2 * r3)     << D4_SHIFT) + d]);
        const f32x4 e1 = __builtin_nontemporal_load(&x[((2 * r3 + 1) << D4_SHIFT) + d]);
        __builtin_nontemporal_store(a0 * w0 + a1 * w1, &out[i0]);
        __builtin_nontemporal_store(b0 * w0 + b1 * w1, &out[i1]);
        __builtin_nontemporal_store(c0 * w0 + c1 * w1, &out[i2]);
        __builtin_nontemporal_store(e0 * w0 + e1 * w1, &out[i3]);
    }
    // tail (not taken at this problem size, but keep general)
    for (; i < n4; i += stride) {
        const int r = i >> D4_SHIFT;
        const f32x4 x0 = __builtin_nontemporal_load(&x[((2 * r)     << D4_SHIFT) + d]);
        const f32x4 x1 = __builtin_nontemporal_load(&x[((2 * r + 1) << D4_SHIFT) + d]);
        __builtin_nontemporal_store(x0 * w0 + x1 * w1, &out[i]);
    }
}

extern "C" void kernel_launch(void* const* d_in, const int* in_sizes, int n_in,
                              void* d_out, int out_size, void* d_ws, size_t ws_size,
                              hipStream_t stream) {
    const f32x4* x = (const f32x4*)d_in[0];
    const f32x4* w = (const f32x4*)d_in[1];
    f32x4* out = (f32x4*)d_out;

    const int n4 = out_size / 4;                 // 8,388,608 float4s

    const int block = 256;
    const int grid = 2048;                       // 8 blocks/CU, 32 waves/CU
    nodeconv_kernel<<<grid, block, 0, stream>>>(x, w, out, n4);
}

// Round 5
// 64.741 us; speedup vs baseline: 1.1995x; 1.1995x over previous
//
#include <hip/hip_runtime.h>

// NodeConvolution: out[b,s,d] = x[b,2s,d]*w[0,d] + x[b,2s+1,d]*w[1,d]
// Shapes: x (32, 4096, 512) f32, w (2, 512) f32, out (32, 2048, 512) f32.
// Memory-bound: ~403 MB HBM traffic. Ladder: R1 79.2 us -> R3 (NT both + 2x) 72.5 us
// (5.57 TB/s). R4 (4x unroll) REGRESSED 77.7 -> revert depth.
// R5: 2x unroll, CACHED loads (L3 may retain x across replays) + NT stores
// (out has no reuse; avoid write-allocate pollution of L3).

#define D4 128          // D/4 float4 per row
#define D4_SHIFT 7      // log2(D4)

typedef float f32x4 __attribute__((ext_vector_type(4)));

__global__ __launch_bounds__(256) void nodeconv_kernel(
    const f32x4* __restrict__ x,   // [B*N][D4]
    const f32x4* __restrict__ w,   // [2][D4]
    f32x4* __restrict__ out,       // [B*steps][D4]
    int n4)
{
    const int stride = gridDim.x * blockDim.x;   // multiple of D4 by construction
    const int tid = blockIdx.x * blockDim.x + threadIdx.x;

    // stride % D4 == 0 -> column index d is loop-invariant per thread
    const int d = tid & (D4 - 1);
    const f32x4 w0 = w[d];          // weights: tiny, cache-resident
    const f32x4 w1 = w[D4 + d];

    int i = tid;
    // main: 2 outputs per iteration (R3's best-known schedule), cached loads
    for (; i + stride < n4; i += 2 * stride) {
        const int ia = i;
        const int ib = i + stride;
        const int ra = ia >> D4_SHIFT;
        const int rb = ib >> D4_SHIFT;
        const f32x4 a0 = x[((2 * ra)     << D4_SHIFT) + d];
        const f32x4 a1 = x[((2 * ra + 1) << D4_SHIFT) + d];
        const f32x4 b0 = x[((2 * rb)     << D4_SHIFT) + d];
        const f32x4 b1 = x[((2 * rb + 1) << D4_SHIFT) + d];
        const f32x4 oa = a0 * w0 + a1 * w1;
        const f32x4 ob = b0 * w0 + b1 * w1;
        __builtin_nontemporal_store(oa, &out[ia]);
        __builtin_nontemporal_store(ob, &out[ib]);
    }
    // tail (not taken at this problem size, but keep general)
    for (; i < n4; i += stride) {
        const int r = i >> D4_SHIFT;
        const f32x4 x0 = x[((2 * r)     << D4_SHIFT) + d];
        const f32x4 x1 = x[((2 * r + 1) << D4_SHIFT) + d];
        __builtin_nontemporal_store(x0 * w0 + x1 * w1, &out[i]);
    }
}

extern "C" void kernel_launch(void* const* d_in, const int* in_sizes, int n_in,
                              void* d_out, int out_size, void* d_ws, size_t ws_size,
                              hipStream_t stream) {
    const f32x4* x = (const f32x4*)d_in[0];
    const f32x4* w = (const f32x4*)d_in[1];
    f32x4* out = (f32x4*)d_out;

    const int n4 = out_size / 4;                 // 8,388,608 float4s

    const int block = 256;
    const int grid = 2048;                       // 8 blocks/CU resident, 32 waves/CU
    nodeconv_kernel<<<grid, block, 0, stream>>>(x, w, out, n4);
}